// Round 15
// baseline (409.760 us; speedup 1.0000x reference)
//
#include <hip/hip_runtime.h>
#include <hip/hip_bf16.h>

typedef __hip_bfloat16 bf16;

// Problem constants (B=32, H=W=56, C=192, NH=6, WS=7)
#define BB 32
#define HH 56
#define WW 56
#define CC 192
#define LL 3136            // 56*56
#define MM (BB*LL)         // 100352 tokens
#define C3 576
#define HIDN 384
#define NHEAD 6
#define HD 32
#define NWIN 2048          // B * 8*8

typedef short short8 __attribute__((ext_vector_type(8)));
typedef float f32x4 __attribute__((ext_vector_type(4)));

__device__ __forceinline__ float us2f(unsigned short u) {
    union { unsigned int i; float f; } v; v.i = ((unsigned int)u) << 16; return v.f;
}
__device__ __forceinline__ float b2f(bf16 h) { return __bfloat162float(h); }
__device__ __forceinline__ bf16 f2b(float f) { return __float2bfloat16(f); }
__device__ __forceinline__ short f2bs(float f) { bf16 h = f2b(f); return *reinterpret_cast<short*>(&h); }
__device__ __forceinline__ unsigned pk2(float a, float b) {
    return (unsigned)(unsigned short)f2bs(a) | ((unsigned)(unsigned short)f2bs(b) << 16);
}
__device__ __forceinline__ float ldv(const bf16* p) { return b2f(*p); }
__device__ __forceinline__ float ldv(const float* p) { return *p; }
__device__ __forceinline__ void stv(bf16* p, float v) { *p = f2b(v); }
__device__ __forceinline__ void stv(float* p, float v) { *p = v; }
__device__ __forceinline__ float gelu_exact(float x) {
    return 0.5f * x * (1.0f + erff(x * 0.70710678118654752f));
}
__device__ __forceinline__ void async_lds16(const void* g, void* l) {
    __builtin_amdgcn_global_load_lds(
        (const __attribute__((address_space(1))) void*)g,
        (__attribute__((address_space(3))) void*)l, 16, 0, 0);
}
// C-layout (row=R,col=Cc) pair -> MFMA A/B fragment (row'=Cc, k=R) [verified in winattn v4]
__device__ __forceinline__ short8 cfrag(const f32x4& A, const f32x4& B,
                                        int src0, int src1, bool hi) {
    unsigned A0 = pk2(A[0], A[1]), A1 = pk2(A[2], A[3]);
    unsigned B0 = pk2(B[0], B[1]), B1 = pk2(B[2], B[3]);
    unsigned xa0 = __shfl(A0, src0, 64), xa1 = __shfl(A1, src0, 64);
    unsigned xa2 = __shfl(A0, src1, 64), xa3 = __shfl(A1, src1, 64);
    unsigned xb0 = __shfl(B0, src0, 64), xb1 = __shfl(B1, src0, 64);
    unsigned xb2 = __shfl(B0, src1, 64), xb3 = __shfl(B1, src1, 64);
    union { unsigned u[4]; short8 s; } ub;
    ub.u[0] = hi ? xb0 : xa0;
    ub.u[1] = hi ? xb1 : xa1;
    ub.u[2] = hi ? xb2 : xa2;
    ub.u[3] = hi ? xb3 : xa3;
    return ub.s;
}

// ---------------- f32 -> bf16 conversion of all 8 weight matrices in one launch ------
__global__ __launch_bounds__(256)
void cvt8_kernel(const float* __restrict__ s0, bf16* __restrict__ d0, int n0,
                 const float* __restrict__ s1, bf16* __restrict__ d1, int n1,
                 const float* __restrict__ s2, bf16* __restrict__ d2, int n2,
                 const float* __restrict__ s3, bf16* __restrict__ d3, int n3,
                 const float* __restrict__ s4, bf16* __restrict__ d4, int n4,
                 const float* __restrict__ s5, bf16* __restrict__ d5, int n5,
                 const float* __restrict__ s6, bf16* __restrict__ d6, int n6,
                 const float* __restrict__ s7, bf16* __restrict__ d7, int n7)
{
    int i = blockIdx.x * 256 + threadIdx.x;
    if (i < n0) { d0[i] = f2b(s0[i]); return; } i -= n0;
    if (i < n1) { d1[i] = f2b(s1[i]); return; } i -= n1;
    if (i < n2) { d2[i] = f2b(s2[i]); return; } i -= n2;
    if (i < n3) { d3[i] = f2b(s3[i]); return; } i -= n3;
    if (i < n4) { d4[i] = f2b(s4[i]); return; } i -= n4;
    if (i < n5) { d5[i] = f2b(s5[i]); return; } i -= n5;
    if (i < n6) { d6[i] = f2b(s6[i]); return; } i -= n6;
    if (i < n7) { d7[i] = f2b(s7[i]); }
}

// ---------------- LayerNorm: one wave per row; optionally also emit bf16 copy of in --
template<typename IT>
__global__ __launch_bounds__(256)
void ln_kernel(const IT* __restrict__ in, const float* __restrict__ g,
               const float* __restrict__ bvec, bf16* __restrict__ out,
               bf16* __restrict__ xcopy)
{
    int wid = threadIdx.x >> 6, lane = threadIdx.x & 63;
    int row = blockIdx.x * 4 + wid;
    const IT* p = in + (size_t)row * CC;
    float x0 = ldv(p + lane);
    float x1 = ldv(p + lane + 64);
    float x2 = ldv(p + lane + 128);
    float s  = x0 + x1 + x2;
    float sq = x0*x0 + x1*x1 + x2*x2;
    #pragma unroll
    for (int o = 32; o > 0; o >>= 1) {
        s  += __shfl_xor(s,  o, 64);
        sq += __shfl_xor(sq, o, 64);
    }
    float mean = s * (1.0f / CC);
    float var  = sq * (1.0f / CC) - mean * mean;
    float inv  = rsqrtf(fmaxf(var, 0.0f) + 1e-5f);
    bf16* q = out + (size_t)row * CC;
    q[lane]       = f2b((x0 - mean) * inv * g[lane]       + bvec[lane]);
    q[lane + 64]  = f2b((x1 - mean) * inv * g[lane + 64]  + bvec[lane + 64]);
    q[lane + 128] = f2b((x2 - mean) * inv * g[lane + 128] + bvec[lane + 128]);
    if (xcopy) {
        bf16* xq = xcopy + (size_t)row * CC;
        xq[lane]       = f2b(x0);
        xq[lane + 64]  = f2b(x1);
        xq[lane + 128] = f2b(x2);
    }
}

// ---------------- MFMA GEMM (R12 config): block tile 128x64, BK=64, 4 waves ---------
// EPI: 0=none, 1=gelu, 2=combine (out = acc + resid + b2f(xn2)*gate[b,c]).
// bf16 output staged through dead As/Bs LDS -> 16B coalesced stores.
template<int EPI, bool RESID, int NN, int KK, typename RT, typename OT>
__global__ __launch_bounds__(256)
void mfma_gemm(const bf16* __restrict__ A, const bf16* __restrict__ W,
               const float* __restrict__ bias, const RT* __restrict__ resid,
               OT* __restrict__ out,
               const bf16* __restrict__ xn2, const float* __restrict__ gate)
{
    __shared__ __align__(16) short Smem[128 * 64 + 64 * 64];
    short* As = Smem;
    short* Bs = Smem + 128 * 64;
    const int t    = threadIdx.x;
    const int lane = t & 63;
    const int w    = t >> 6;        // wave 0..3
    const int nx   = gridDim.x;
    const int nwg  = gridDim.x * gridDim.y;
    int hw  = blockIdx.y * nx + blockIdx.x;
    int wid = (nwg & 7) ? hw : ((hw & 7) * (nwg >> 3) + (hw >> 3));
    const int m0   = (wid / nx) * 128;
    const int n0   = (wid % nx) * 64;
    const int lr   = lane & 15;
    const int lg   = lane >> 4;

    f32x4 acc[2][4];
    #pragma unroll
    for (int i = 0; i < 2; ++i)
        #pragma unroll
        for (int j = 0; j < 4; ++j)
            acc[i][j] = (f32x4){0.f, 0.f, 0.f, 0.f};

    for (int k0 = 0; k0 < KK; k0 += 64) {
        const bf16* Ab = A + (size_t)m0 * KK + k0;
        const bf16* Wb = W + (size_t)n0 * KK + k0;
        #pragma unroll
        for (int li = 0; li < 4; ++li) {
            int chunk = li * 256 + t;
            int r = chunk >> 3, c = chunk & 7;
            int cs = c ^ (r & 7);
            async_lds16(Ab + (size_t)r * KK + (cs << 3),
                        &As[(li * 256 + w * 64) << 3]);
        }
        #pragma unroll
        for (int li = 0; li < 2; ++li) {
            int chunk = li * 256 + t;
            int r = chunk >> 3, c = chunk & 7;
            int cs = c ^ (r & 7);
            async_lds16(Wb + (size_t)r * KK + (cs << 3),
                        &Bs[(li * 256 + w * 64) << 3]);
        }
        __syncthreads();
        #pragma unroll
        for (int kf = 0; kf < 2; ++kf) {
            short8 a_[2], b_[4];
            #pragma unroll
            for (int mi = 0; mi < 2; ++mi) {
                int row = (w << 5) + (mi << 4) + lr;
                a_[mi] = *reinterpret_cast<const short8*>(
                    &As[(row << 6) + ((((kf << 2) + lg) ^ (row & 7)) << 3)]);
            }
            #pragma unroll
            for (int ni = 0; ni < 4; ++ni) {
                int rn = (ni << 4) + lr;
                b_[ni] = *reinterpret_cast<const short8*>(
                    &Bs[(rn << 6) + ((((kf << 2) + lg) ^ (rn & 7)) << 3)]);
            }
            #pragma unroll
            for (int mi = 0; mi < 2; ++mi)
                #pragma unroll
                for (int ni = 0; ni < 4; ++ni)
                    acc[mi][ni] = __builtin_amdgcn_mfma_f32_16x16x32_bf16(
                        a_[mi], b_[ni], acc[mi][ni], 0, 0, 0);
        }
        __syncthreads();
    }

    if constexpr (sizeof(OT) == 2) {
        short* cs = Smem + w * 3072;
        #pragma unroll
        for (int mi = 0; mi < 2; ++mi) {
            #pragma unroll
            for (int ni = 0; ni < 4; ++ni) {
                int col = n0 + (ni << 4) + lr;
                float bv = bias ? bias[col] : 0.f;
                #pragma unroll
                for (int r = 0; r < 4; ++r) {
                    int row = m0 + (w << 5) + (mi << 4) + (lg << 2) + r;
                    float c = acc[mi][ni][r] + bv;
                    if (EPI == 1) c = gelu_exact(c);
                    if (EPI == 2) {
                        int bidx = row / LL;
                        c += ldv(resid + (size_t)row * NN + col)
                           + b2f(xn2[(size_t)row * NN + col]) * gate[bidx * CC + col];
                    }
                    if (RESID) c += ldv(resid + (size_t)row * NN + col);
                    cs[((mi << 4) + (lg << 2) + r) * 72 + (ni << 4) + lr] = f2bs(c);
                }
            }
        }
        #pragma unroll
        for (int pass = 0; pass < 4; ++pass) {
            int r8 = (lane >> 3) + (pass << 3);
            int c8 = lane & 7;
            uint4 v = *reinterpret_cast<const uint4*>(&cs[r8 * 72 + (c8 << 3)]);
            *reinterpret_cast<uint4*>((bf16*)out + (size_t)(m0 + (w << 5) + r8) * NN
                                      + n0 + (c8 << 3)) = v;
        }
    } else {
        #pragma unroll
        for (int mi = 0; mi < 2; ++mi) {
            #pragma unroll
            for (int ni = 0; ni < 4; ++ni) {
                int col = n0 + (ni << 4) + lr;
                float bv = bias ? bias[col] : 0.f;
                #pragma unroll
                for (int r = 0; r < 4; ++r) {
                    int row = m0 + (w << 5) + (mi << 4) + (lg << 2) + r;
                    float c = acc[mi][ni][r] + bv;
                    if (EPI == 1) c = gelu_exact(c);
                    if (EPI == 2) {
                        int bidx = row / LL;
                        c += ldv(resid + (size_t)row * NN + col)
                           + b2f(xn2[(size_t)row * NN + col]) * gate[bidx * CC + col];
                    }
                    if (RESID) c += ldv(resid + (size_t)row * NN + col);
                    stv(out + (size_t)row * NN + col, c);
                }
            }
        }
    }
}

// ---------------- FUSED qkv-projection + window attention -------------------------
// One block per window (2048), 384 threads = 6 waves = 6 heads.
// Shared xn tile 64x192 (chunk-XOR swizzled, rows>=49 zero), staged once.
// Per wave: Q^T,K^T (A=weights, B=xn) and V (A=xn, B=weights) via MFMA; the
// verified cfrag transform turns each C-result into the attention fragments.
// Attention = winattn v4 (swapped S^T, in-register softmax with key masks, PV).
__global__ __launch_bounds__(384)
void qkvattn_kernel(const bf16* __restrict__ xn, const bf16* __restrict__ wqkv,
                    const float* __restrict__ qbias, bf16* __restrict__ aw)
{
    __shared__ __align__(16) short Smem[64 * 192];   // 24KB, reused for output staging

    const int w    = threadIdx.x >> 6;   // wave = head 0..5
    const int lane = threadIdx.x & 63;
    const int wi   = blockIdx.x;
    const int b  = wi >> 6;
    const int wr = wi & 63;
    const int wy = wr >> 3, wx = wr & 7;
    const int lc = lane & 15;
    const int lg = lane >> 4;
    const float scale = 0.1767766952966369f;   // 32^-0.5
    const bf16* xbase = xn + (size_t)b * LL * CC;

    // stage xn window tile (64x192), rows >= 49 zeroed
    #pragma unroll
    for (int li = 0; li < 4; ++li) {
        int chunk = li * 384 + threadIdx.x;
        int tok = chunk / 24, c = chunk - tok * 24;
        if (tok < 49) {
            int iy = tok / 7, ix = tok - iy * 7;
            size_t l = (size_t)(wy * 7 + iy) * 56 + wx * 7 + ix;
            int cs = (c & ~7) | ((c & 7) ^ (tok & 7));
            async_lds16(xbase + l * CC + (cs << 3), &Smem[(li * 384 + w * 64) << 3]);
        } else {
            *reinterpret_cast<uint4*>(&Smem[chunk << 3]) = (uint4){0, 0, 0, 0};
        }
    }
    __syncthreads();

    const int src0 = ((lg & 1) << 5) + lc;
    const int src1 = src0 + 16;
    const bool hi = (lg >> 1) != 0;
    const int qrow = w * HD;             // Q weight row base for this head

    // Q^T = Wq . xn^T : C[d(2 tiles)][tok(4 tiles)]
    short8 qb[4], ka[4], vfrag[2][2];
    {
        f32x4 aq[2][4];
        #pragma unroll
        for (int i = 0; i < 2; ++i)
            #pragma unroll
            for (int j = 0; j < 4; ++j)
                aq[i][j] = (f32x4){0.f, 0.f, 0.f, 0.f};
        #pragma unroll
        for (int kf = 0; kf < 6; ++kf) {
            short8 a0 = *reinterpret_cast<const short8*>(
                wqkv + (size_t)(qrow + lc) * CC + (kf << 5) + (lg << 3));
            short8 a1 = *reinterpret_cast<const short8*>(
                wqkv + (size_t)(qrow + 16 + lc) * CC + (kf << 5) + (lg << 3));
            #pragma unroll
            for (int nj = 0; nj < 4; ++nj) {
                int row = (nj << 4) + lc;
                int cc = (kf << 2) + lg;
                int cs = (cc & ~7) | ((cc & 7) ^ (row & 7));
                short8 bx = *reinterpret_cast<const short8*>(&Smem[row * 192 + (cs << 3)]);
                aq[0][nj] = __builtin_amdgcn_mfma_f32_16x16x32_bf16(a0, bx, aq[0][nj], 0, 0, 0);
                aq[1][nj] = __builtin_amdgcn_mfma_f32_16x16x32_bf16(a1, bx, aq[1][nj], 0, 0, 0);
            }
        }
        #pragma unroll
        for (int mi = 0; mi < 2; ++mi) {
            float bv = qbias[qrow + (mi << 4) + (lg << 2)];
            float b1 = qbias[qrow + (mi << 4) + (lg << 2) + 1];
            float b2 = qbias[qrow + (mi << 4) + (lg << 2) + 2];
            float b3 = qbias[qrow + (mi << 4) + (lg << 2) + 3];
            #pragma unroll
            for (int nj = 0; nj < 4; ++nj) {
                aq[mi][nj][0] += bv; aq[mi][nj][1] += b1;
                aq[mi][nj][2] += b2; aq[mi][nj][3] += b3;
            }
        }
        #pragma unroll
        for (int nj = 0; nj < 4; ++nj)
            qb[nj] = cfrag(aq[0][nj], aq[1][nj], src0, src1, hi);
    }
    // K^T
    {
        f32x4 ak[2][4];
        #pragma unroll
        for (int i = 0; i < 2; ++i)
            #pragma unroll
            for (int j = 0; j < 4; ++j)
                ak[i][j] = (f32x4){0.f, 0.f, 0.f, 0.f};
        #pragma unroll
        for (int kf = 0; kf < 6; ++kf) {
            short8 a0 = *reinterpret_cast<const short8*>(
                wqkv + (size_t)(CC + qrow + lc) * CC + (kf << 5) + (lg << 3));
            short8 a1 = *reinterpret_cast<const short8*>(
                wqkv + (size_t)(CC + qrow + 16 + lc) * CC + (kf << 5) + (lg << 3));
            #pragma unroll
            for (int nj = 0; nj < 4; ++nj) {
                int row = (nj << 4) + lc;
                int cc = (kf << 2) + lg;
                int cs = (cc & ~7) | ((cc & 7) ^ (row & 7));
                short8 bx = *reinterpret_cast<const short8*>(&Smem[row * 192 + (cs << 3)]);
                ak[0][nj] = __builtin_amdgcn_mfma_f32_16x16x32_bf16(a0, bx, ak[0][nj], 0, 0, 0);
                ak[1][nj] = __builtin_amdgcn_mfma_f32_16x16x32_bf16(a1, bx, ak[1][nj], 0, 0, 0);
            }
        }
        #pragma unroll
        for (int mi = 0; mi < 2; ++mi) {
            float b0 = qbias[CC + qrow + (mi << 4) + (lg << 2)];
            float b1 = qbias[CC + qrow + (mi << 4) + (lg << 2) + 1];
            float b2 = qbias[CC + qrow + (mi << 4) + (lg << 2) + 2];
            float b3 = qbias[CC + qrow + (mi << 4) + (lg << 2) + 3];
            #pragma unroll
            for (int nj = 0; nj < 4; ++nj) {
                ak[mi][nj][0] += b0; ak[mi][nj][1] += b1;
                ak[mi][nj][2] += b2; ak[mi][nj][3] += b3;
            }
        }
        #pragma unroll
        for (int nj = 0; nj < 4; ++nj)
            ka[nj] = cfrag(ak[0][nj], ak[1][nj], src0, src1, hi);
    }
    // V = xn . Wv^T : C[tok(4 tiles)][d(2 tiles)]
    {
        f32x4 av[4][2];
        #pragma unroll
        for (int i = 0; i < 4; ++i)
            #pragma unroll
            for (int j = 0; j < 2; ++j)
                av[i][j] = (f32x4){0.f, 0.f, 0.f, 0.f};
        #pragma unroll
        for (int kf = 0; kf < 6; ++kf) {
            short8 bw[2];
            #pragma unroll
            for (int nj = 0; nj < 2; ++nj)
                bw[nj] = *reinterpret_cast<const short8*>(
                    wqkv + (size_t)(2 * CC + qrow + (nj << 4) + lc) * CC + (kf << 5) + (lg << 3));
            #pragma unroll
            for (int mi = 0; mi < 4; ++mi) {
                int row = (mi << 4) + lc;
                int cc = (kf << 2) + lg;
                int cs = (cc & ~7) | ((cc & 7) ^ (row & 7));
                short8 ax = *reinterpret_cast<const short8*>(&Smem[row * 192 + (cs << 3)]);
                #pragma unroll
                for (int nj = 0; nj < 2; ++nj)
                    av[mi][nj] = __builtin_amdgcn_mfma_f32_16x16x32_bf16(ax, bw[nj], av[mi][nj], 0, 0, 0);
            }
        }
        #pragma unroll
        for (int nj = 0; nj < 2; ++nj) {
            float bv = qbias[2 * CC + qrow + (nj << 4) + lc];
            #pragma unroll
            for (int mi = 0; mi < 4; ++mi) {
                av[mi][nj][0] += bv; av[mi][nj][1] += bv;
                av[mi][nj][2] += bv; av[mi][nj][3] += bv;
            }
        }
        #pragma unroll
        for (int kf = 0; kf < 2; ++kf)
            #pragma unroll
            for (int mi2 = 0; mi2 < 2; ++mi2)
                vfrag[kf][mi2] = cfrag(av[2*kf][mi2], av[2*kf+1][mi2], src0, src1, hi);
    }

    // S^T = K Q^T : acc[mi(key-tile)][nj(tok-tile)], K=32 single MFMA each
    f32x4 acc[4][4];
    #pragma unroll
    for (int mi = 0; mi < 4; ++mi)
        #pragma unroll
        for (int nj = 0; nj < 4; ++nj)
            acc[mi][nj] = __builtin_amdgcn_mfma_f32_16x16x32_bf16(
                ka[mi], qb[nj], (f32x4){0.f, 0.f, 0.f, 0.f}, 0, 0, 0);

    // softmax over keys (rows). keys mi<3 valid; mi==3: only key 48 (lg==0,r==0).
    float rinv[4];
    #pragma unroll
    for (int nj = 0; nj < 4; ++nj) {
        float mx = acc[0][nj][0];
        #pragma unroll
        for (int mi = 0; mi < 3; ++mi)
            #pragma unroll
            for (int r = 0; r < 4; ++r)
                mx = fmaxf(mx, acc[mi][nj][r]);
        float v48 = (lg == 0) ? acc[3][nj][0] : -1e30f;
        mx = fmaxf(mx, v48);
        mx = fmaxf(mx, __shfl_xor(mx, 16, 64));
        mx = fmaxf(mx, __shfl_xor(mx, 32, 64));
        float sm = 0.f;
        #pragma unroll
        for (int mi = 0; mi < 3; ++mi)
            #pragma unroll
            for (int r = 0; r < 4; ++r) {
                float e = __expf(scale * (acc[mi][nj][r] - mx));
                acc[mi][nj][r] = e;
                sm += e;
            }
        float e48 = (lg == 0) ? __expf(scale * (acc[3][nj][0] - mx)) : 0.f;
        acc[3][nj][0] = e48; sm += e48;
        acc[3][nj][1] = 0.f; acc[3][nj][2] = 0.f; acc[3][nj][3] = 0.f;
        sm += __shfl_xor(sm, 16, 64);
        sm += __shfl_xor(sm, 32, 64);
        rinv[nj] = 1.0f / sm;
    }

    // O^T = V^T P^T
    f32x4 o2[2][4];
    #pragma unroll
    for (int i = 0; i < 2; ++i)
        #pragma unroll
        for (int j = 0; j < 4; ++j)
            o2[i][j] = (f32x4){0.f, 0.f, 0.f, 0.f};
    #pragma unroll
    for (int kf = 0; kf < 2; ++kf) {
        #pragma unroll
        for (int nj = 0; nj < 4; ++nj) {
            short8 ub = cfrag(acc[2*kf][nj], acc[2*kf+1][nj], src0, src1, hi);
            #pragma unroll
            for (int mi2 = 0; mi2 < 2; ++mi2)
                o2[mi2][nj] = __builtin_amdgcn_mfma_f32_16x16x32_bf16(
                    vfrag[kf][mi2], ub, o2[mi2][nj], 0, 0, 0);
        }
    }

    // all waves done reading shared xn tile -> reuse for per-wave output staging
    __syncthreads();
    short* obuf = Smem + w * 2048;    // 49 rows x stride 40 = 1960 <= 2048
    #pragma unroll
    for (int mi2 = 0; mi2 < 2; ++mi2)
        #pragma unroll
        for (int nj = 0; nj < 4; ++nj) {
            int tok = (nj << 4) + lc;
            if (tok < 49) {
                #pragma unroll
                for (int r = 0; r < 4; ++r) {
                    int d = (mi2 << 4) + (lg << 2) + r;
                    obuf[tok * 40 + d] = f2bs(o2[mi2][nj][r] * rinv[nj]);
                }
            }
        }
    for (int e = lane; e < 196; e += 64) {
        int tok = e >> 2, part = e & 3;
        int iy = tok / 7, ix = tok - iy * 7;
        size_t l = (size_t)(wy * 7 + iy) * 56 + wx * 7 + ix;
        *reinterpret_cast<uint4*>(aw + ((size_t)b * LL + l) * CC + w * HD + (part << 3)) =
            *reinterpret_cast<const uint4*>(&obuf[tok * 40 + (part << 3)]);
    }
}

// ---------------- Depthwise 3x3 (SAME) + exact GELU, vectorized 8-ch/thread ----------
__global__ __launch_bounds__(256)
void dwconv_kernel(const bf16* __restrict__ xn, const float* __restrict__ w,
                   bf16* __restrict__ out)
{
    __shared__ float wl[9 * 288];
    const int t = threadIdx.x;
    for (int i = t; i < CC * 9; i += 256) {
        int c = i / 9, k = i - c * 9;
        wl[k * 288 + (c >> 3) * 12 + (c & 7)] = w[i];
    }
    __syncthreads();
    int e = blockIdx.x * 256 + t;
    int cg = e % 24;
    int pix = e / 24;
    int w_ = pix % WW;
    int t2 = pix / WW;
    int h_ = t2 % HH;
    int b  = t2 / HH;
    float acc[8] = {0.f,0.f,0.f,0.f,0.f,0.f,0.f,0.f};
    const bf16* rowbase = xn + ((size_t)b * HH * WW) * CC + (size_t)cg * 8;
    #pragma unroll
    for (int ky = 0; ky < 3; ++ky) {
        int hy = h_ + ky - 1;
        if (hy < 0 || hy >= HH) continue;
        #pragma unroll
        for (int kx = 0; kx < 3; ++kx) {
            int wx_ = w_ + kx - 1;
            if (wx_ < 0 || wx_ >= WW) continue;
            int k = ky * 3 + kx;
            const float4* wp = reinterpret_cast<const float4*>(&wl[k * 288 + cg * 12]);
            float4 w0 = wp[0];
            float4 w1 = wp[1];
            unsigned short u[8];
            *reinterpret_cast<uint4*>(u) = *reinterpret_cast<const uint4*>(
                rowbase + ((size_t)hy * WW + wx_) * CC);
            acc[0] += us2f(u[0]) * w0.x;
            acc[1] += us2f(u[1]) * w0.y;
            acc[2] += us2f(u[2]) * w0.z;
            acc[3] += us2f(u[3]) * w0.w;
            acc[4] += us2f(u[4]) * w1.x;
            acc[5] += us2f(u[5]) * w1.y;
            acc[6] += us2f(u[6]) * w1.z;
            acc[7] += us2f(u[7]) * w1.w;
        }
    }
    bf16 o8[8];
    #pragma unroll
    for (int j = 0; j < 8; ++j) o8[j] = f2b(gelu_exact(acc[j]));
    *reinterpret_cast<uint4*>(out + (size_t)e * 8) = *reinterpret_cast<uint4*>(o8);
}

// ---------------- column (spatial) sum of xn per (b, c) ----------------
__global__ __launch_bounds__(192)
void colsum_kernel(const bf16* __restrict__ xn, float* __restrict__ colsum)
{
    int b = blockIdx.y, g = blockIdx.x, c = threadIdx.x;
    float acc = 0.f;
    int l0 = g * 196;
    for (int l = l0; l < l0 + 196; ++l)
        acc += b2f(xn[((size_t)b * LL + l) * CC + c]);
    atomicAdd(&colsum[b * CC + c], acc);
}

__global__ __launch_bounds__(192)
void gate_kernel(const float* __restrict__ colsum, const float* __restrict__ gw,
                 const float* __restrict__ gb, float* __restrict__ gate)
{
    __shared__ float cm[CC];
    int b = blockIdx.x, o = threadIdx.x;
    cm[o] = colsum[b * CC + o] * (1.0f / LL);
    __syncthreads();
    float acc = gb[o];
    for (int c = 0; c < CC; ++c) acc += gw[o * CC + c] * cm[c];
    gate[b * CC + o] = 1.0f / (1.0f + expf(-acc));
}

// ---------------- means over H and W in one launch, vec8, bf16 out ----------------
__global__ __launch_bounds__(256)
void means_kernel(const bf16* __restrict__ xf, bf16* __restrict__ mh,
                  bf16* __restrict__ mw)
{
    int e = blockIdx.x * 256 + threadIdx.x;
    const int NHALF = BB * WW * 24;
    if (e < NHALF) {
        int cg = e % 24, c0 = cg << 3;
        int w_ = (e / 24) % WW;
        int b  = e / (24 * WW);
        float s[8] = {0.f,0.f,0.f,0.f,0.f,0.f,0.f,0.f};
        const bf16* base = xf + ((size_t)b * HH * WW + w_) * CC + c0;
        for (int h_ = 0; h_ < HH; ++h_) {
            unsigned short u[8];
            *reinterpret_cast<uint4*>(u) = *reinterpret_cast<const uint4*>(base + (size_t)h_ * WW * CC);
            #pragma unroll
            for (int j = 0; j < 8; ++j) s[j] += us2f(u[j]);
        }
        bf16 o8[8];
        #pragma unroll
        for (int j = 0; j < 8; ++j) o8[j] = f2b(s[j] * (1.0f / HH));
        *reinterpret_cast<uint4*>(mh + ((size_t)b * WW + w_) * CC + c0) =
            *reinterpret_cast<uint4*>(o8);
    } else {
        e -= NHALF;
        int cg = e % 24, c0 = cg << 3;
        int h_ = (e / 24) % HH;
        int b  = e / (24 * HH);
        float s[8] = {0.f,0.f,0.f,0.f,0.f,0.f,0.f,0.f};
        const bf16* base = xf + ((size_t)b * HH + h_) * WW * CC + c0;
        for (int w_ = 0; w_ < WW; ++w_) {
            unsigned short u[8];
            *reinterpret_cast<uint4*>(u) = *reinterpret_cast<const uint4*>(base + (size_t)w_ * CC);
            #pragma unroll
            for (int j = 0; j < 8; ++j) s[j] += us2f(u[j]);
        }
        bf16 o8[8];
        #pragma unroll
        for (int j = 0; j < 8; ++j) o8[j] = f2b(s[j] * (1.0f / WW));
        *reinterpret_cast<uint4*>(mw + ((size_t)b * HH + h_) * CC + c0) =
            *reinterpret_cast<uint4*>(o8);
    }
}

// ---------------- MFMA axis softmax ----------------
__global__ __launch_bounds__(256)
void axmfma_kernel(const bf16* __restrict__ mh, const bf16* __restrict__ wt,
                   float* __restrict__ at,
                   const bf16* __restrict__ mw, const bf16* __restrict__ ws,
                   float* __restrict__ as_)
{
    const int b = blockIdx.x;
    const bf16* mean; const bf16* wmat; float* out;
    if (blockIdx.y == 0) { mean = mh; wmat = wt; out = at; }
    else                 { mean = mw; wmat = ws; out = as_; }
    const int w  = threadIdx.x >> 6;
    const int t  = threadIdx.x & 63;
    const int lc = t & 15, lg = t >> 4;
    const bf16* mb = mean + (size_t)b * 56 * CC;
    const short8 zero8 = {0, 0, 0, 0, 0, 0, 0, 0};

    f32x4 acc[3][4];
    #pragma unroll
    for (int i = 0; i < 3; ++i)
        #pragma unroll
        for (int j = 0; j < 4; ++j)
            acc[i][j] = (f32x4){0.f, 0.f, 0.f, 0.f};

    #pragma unroll
    for (int kf = 0; kf < 6; ++kf) {
        short8 a_[3], b_[4];
        #pragma unroll
        for (int mi = 0; mi < 3; ++mi) {
            int o = ((w * 3 + mi) << 4) + lc;
            a_[mi] = *reinterpret_cast<const short8*>(wmat + (size_t)o * CC + (kf << 5) + (lg << 3));
        }
        #pragma unroll
        for (int ni = 0; ni < 4; ++ni) {
            int pos = (ni << 4) + lc;
            b_[ni] = (pos < 56)
                ? *reinterpret_cast<const short8*>(mb + (size_t)pos * CC + (kf << 5) + (lg << 3))
                : zero8;
        }
        #pragma unroll
        for (int mi = 0; mi < 3; ++mi)
            #pragma unroll
            for (int ni = 0; ni < 4; ++ni)
                acc[mi][ni] = __builtin_amdgcn_mfma_f32_16x16x32_bf16(
                    a_[mi], b_[ni], acc[mi][ni], 0, 0, 0);
    }

    #pragma unroll
    for (int mi = 0; mi < 3; ++mi) {
        #pragma unroll
        for (int r = 0; r < 4; ++r) {
            float mx = -1e30f;
            #pragma unroll
            for (int ni = 0; ni < 4; ++ni) {
                float v = acc[mi][ni][r];
                if (ni == 3 && lc >= 8) v = -1e30f;
                mx = fmaxf(mx, v);
            }
            mx = fmaxf(mx, __shfl_xor(mx, 1, 64));
            mx = fmaxf(mx, __shfl_xor(mx, 2, 64));
            mx = fmaxf(mx, __shfl_xor(mx, 4, 64));
            mx = fmaxf(mx, __shfl_xor(mx, 8, 64));
            float e[4];
            float sm = 0.f;
            #pragma unroll
            for (int ni = 0; ni < 4; ++ni) {
                e[ni] = (ni == 3 && lc >= 8) ? 0.f : __expf(acc[mi][ni][r] - mx);
                sm += e[ni];
            }
            sm += __shfl_xor(sm, 1, 64);
            sm += __shfl_xor(sm, 2, 64);
            sm += __shfl_xor(sm, 4, 64);
            sm += __shfl_xor(sm, 8, 64);
            float inv = 1.0f / sm;
            int o = ((w * 3 + mi) << 4) + (lg << 2) + r;
            #pragma unroll
            for (int ni = 0; ni < 4; ++ni) {
                int pos = (ni << 4) + lc;
                if (pos < 56)
                    out[((size_t)b * 56 + pos) * CC + o] = e[ni] * inv;
            }
        }
    }
}

// ---------------- xf2 = xf * a_s[b,h,c] * a_t[b,w,c] * 2  (vec8, coalesced) ----------
__global__ __launch_bounds__(256)
void modulate_kernel(const bf16* __restrict__ xf, const float* __restrict__ a_s,
                     const float* __restrict__ a_t, bf16* __restrict__ xf2)
{
    int e = blockIdx.x * 256 + threadIdx.x;
    int cg = e % 24, c0 = cg << 3;
    int pix = e / 24;
    int w_ = pix % WW;
    int t2 = pix / WW;
    int h_ = t2 % HH;
    int b  = t2 / HH;
    unsigned short u[8];
    size_t base = (size_t)e * 8;
    *reinterpret_cast<uint4*>(u) = *reinterpret_cast<const uint4*>(xf + base);
    const float4* sp = reinterpret_cast<const float4*>(a_s + ((size_t)b * 56 + h_) * CC + c0);
    const float4* tp = reinterpret_cast<const float4*>(a_t + ((size_t)b * 56 + w_) * CC + c0);
    float4 s0 = sp[0], s1 = sp[1];
    float4 t0 = tp[0], t1 = tp[1];
    float ss[8] = {s0.x, s0.y, s0.z, s0.w, s1.x, s1.y, s1.z, s1.w};
    float tt[8] = {t0.x, t0.y, t0.z, t0.w, t1.x, t1.y, t1.z, t1.w};
    bf16 o8[8];
    #pragma unroll
    for (int j = 0; j < 8; ++j)
        o8[j] = f2b(us2f(u[j]) * ss[j] * tt[j] * 2.0f);
    *reinterpret_cast<uint4*>(xf2 + base) = *reinterpret_cast<uint4*>(o8);
}

// =======================================================================================
extern "C" void kernel_launch(void* const* d_in, const int* in_sizes, int n_in,
                              void* d_out, int out_size, void* d_ws, size_t ws_size,
                              hipStream_t stream)
{
    const float* x      = (const float*)d_in[0];
    const float* ln1_g  = (const float*)d_in[3];
    const float* ln1_b  = (const float*)d_in[4];
    const float* qkv_w  = (const float*)d_in[5];
    const float* qkv_b  = (const float*)d_in[6];
    const float* proj_w = (const float*)d_in[7];
    const float* proj_b = (const float*)d_in[8];
    const float* dw_w   = (const float*)d_in[9];
    const float* pw_w   = (const float*)d_in[10];
    const float* gate_w = (const float*)d_in[11];
    const float* gate_b = (const float*)d_in[12];
    const float* temp_w = (const float*)d_in[13];
    const float* spec_w = (const float*)d_in[15];
    const float* fuse_w = (const float*)d_in[17];
    const float* ln2_g  = (const float*)d_in[18];
    const float* ln2_b  = (const float*)d_in[19];
    const float* mlp1_w = (const float*)d_in[20];
    const float* mlp1_b = (const float*)d_in[21];
    const float* mlp2_w = (const float*)d_in[22];
    const float* mlp2_b = (const float*)d_in[23];
    float* out = (float*)d_out;

    const size_t SLOT = (size_t)MM * CC * sizeof(bf16);   // 38,535,168 B
    char* ws = (char*)d_ws;

    bf16* s_xn    = (bf16*)(ws);
    bf16* s_aw    = (bf16*)(ws + 4 * SLOT);
    bf16* s_xattn = (bf16*)(ws + SLOT);
    bf16* s_dwg   = (bf16*)(ws + 2 * SLOT);
    bf16* s_xf    = (bf16*)(ws + 4 * SLOT);    // reuse aw (combine fused into pw gemm)
    bf16* s_xf2   = (bf16*)(ws + 3 * SLOT);
    bf16* s_x2    = (bf16*)(ws);               // reuse xn (xn dead after pw+combine)
    bf16* s_hn    = (bf16*)(ws + 2 * SLOT);
    bf16* s_h1    = (bf16*)(ws + 3 * SLOT);    // spans slots 3..4 (384 ch)

    float* colsum  = (float*)(ws + 5 * SLOT);
    float* gatebuf = colsum + BB * CC;
    bf16*  mean_h  = (bf16*)(gatebuf + BB * CC);
    bf16*  mean_w  = mean_h + (size_t)BB * 56 * CC;
    float* a_t     = (float*)(mean_w + (size_t)BB * 56 * CC);
    float* a_s     = a_t + (size_t)BB * CC * 56;
    // bf16 weight copies
    bf16* wb_qkv  = (bf16*)(a_s + (size_t)BB * CC * 56);
    bf16* wb_proj = wb_qkv  + C3 * CC;
    bf16* wb_pw   = wb_proj + CC * CC;
    bf16* wb_fuse = wb_pw   + CC * CC;
    bf16* wb_mlp1 = wb_fuse + CC * CC;
    bf16* wb_mlp2 = wb_mlp1 + HIDN * CC;
    bf16* wb_temp = wb_mlp2 + CC * HIDN;
    bf16* wb_spec = wb_temp + CC * CC;
    char* after_w = (char*)(wb_spec + CC * CC);
    size_t total_need = after_w - ws;
    if (ws_size < total_need) return;   // workspace insufficient — visible failure
    bf16* s_xb = (bf16*)after_w;
    bool have_xb = (ws_size >= total_need + SLOT);

    const int VEC_BLOCKS = MM * 24 / 256;   // 9408, exact
    const int CVT_N0 = C3 * CC, CVT_N1 = CC * CC, CVT_N4 = HIDN * CC;
    const int CVT_TOTAL = CVT_N0 + 5 * CVT_N1 + 2 * CVT_N4;

    // 0. all weight conversions in one launch
    cvt8_kernel<<<(CVT_TOTAL + 255) / 256, 256, 0, stream>>>(
        qkv_w, wb_qkv, CVT_N0, proj_w, wb_proj, CVT_N1, pw_w, wb_pw, CVT_N1,
        fuse_w, wb_fuse, CVT_N1, mlp1_w, wb_mlp1, CVT_N4, mlp2_w, wb_mlp2, CVT_N4,
        temp_w, wb_temp, CVT_N1, spec_w, wb_spec, CVT_N1);

    // 1. LN1 (+ optional bf16 x copy)
    ln_kernel<float><<<MM / 4, 256, 0, stream>>>(x, ln1_g, ln1_b, s_xn,
                                                 have_xb ? s_xb : nullptr);
    // 2. FUSED qkv projection + window attention (no qkv buffer round-trip)
    qkvattn_kernel<<<NWIN, 384, 0, stream>>>(s_xn, wb_qkv, qkv_b, s_aw);
    // 3. proj
    mfma_gemm<0, false, CC, CC, bf16, bf16><<<dim3(CC / 64, MM / 128), 256, 0, stream>>>(
        s_aw, wb_proj, proj_b, (const bf16*)nullptr, s_xattn, nullptr, nullptr);
    // 4. depthwise + gelu (vec8)
    dwconv_kernel<<<VEC_BLOCKS, 256, 0, stream>>>(s_xn, dw_w, s_dwg);
    // 5. gate (needs only xn)
    hipMemsetAsync(colsum, 0, BB * CC * sizeof(float), stream);
    colsum_kernel<<<dim3(16, BB), 192, 0, stream>>>(s_xn, colsum);
    gate_kernel<<<BB, 192, 0, stream>>>(colsum, gate_w, gate_b, gatebuf);
    // 6. pointwise + fused combine: xf = dwg@pw^T + xattn + xn*gate
    mfma_gemm<2, false, CC, CC, bf16, bf16><<<dim3(CC / 64, MM / 128), 256, 0, stream>>>(
        s_dwg, wb_pw, (const float*)nullptr, s_xattn, s_xf, s_xn, gatebuf);
    // 7. axis means (one launch, bf16 out)
    means_kernel<<<(2 * BB * WW * 24) / 256, 256, 0, stream>>>(s_xf, mean_h, mean_w);
    // 8. both axis softmaxes via MFMA
    axmfma_kernel<<<dim3(BB, 2), 256, 0, stream>>>(
        mean_h, wb_temp, a_t, mean_w, wb_spec, a_s);
    // 9. modulate (coalesced)
    modulate_kernel<<<VEC_BLOCKS, 256, 0, stream>>>(s_xf, a_s, a_t, s_xf2);
    // 10. fuse (no bias) + residual x -> x2
    if (have_xb)
        mfma_gemm<0, true, CC, CC, bf16, bf16><<<dim3(CC / 64, MM / 128), 256, 0, stream>>>(
            s_xf2, wb_fuse, (const float*)nullptr, s_xb, s_x2, nullptr, nullptr);
    else
        mfma_gemm<0, true, CC, CC, float, bf16><<<dim3(CC / 64, MM / 128), 256, 0, stream>>>(
            s_xf2, wb_fuse, (const float*)nullptr, x, s_x2, nullptr, nullptr);
    // 11. LN2
    ln_kernel<bf16><<<MM / 4, 256, 0, stream>>>(s_x2, ln2_g, ln2_b, s_hn, nullptr);
    // 12. MLP1 + gelu
    mfma_gemm<1, false, HIDN, CC, bf16, bf16><<<dim3(HIDN / 64, MM / 128), 256, 0, stream>>>(
        s_hn, wb_mlp1, mlp1_b, (const bf16*)nullptr, s_h1, nullptr, nullptr);
    // 13. MLP2 + residual -> out (f32)
    mfma_gemm<0, true, CC, HIDN, bf16, float><<<dim3(CC / 64, MM / 128), 256, 0, stream>>>(
        s_h1, wb_mlp2, mlp2_b, s_x2, out, nullptr, nullptr);
}

// Round 16
// 357.717 us; speedup vs baseline: 1.1455x; 1.1455x over previous
//
#include <hip/hip_runtime.h>
#include <hip/hip_bf16.h>

typedef __hip_bfloat16 bf16;

// Problem constants (B=32, H=W=56, C=192, NH=6, WS=7)
#define BB 32
#define HH 56
#define WW 56
#define CC 192
#define LL 3136            // 56*56
#define MM (BB*LL)         // 100352 tokens
#define C3 576
#define HIDN 384
#define NHEAD 6
#define HD 32
#define NWIN 2048          // B * 8*8

typedef short short8 __attribute__((ext_vector_type(8)));
typedef float f32x4 __attribute__((ext_vector_type(4)));

__device__ __forceinline__ float us2f(unsigned short u) {
    union { unsigned int i; float f; } v; v.i = ((unsigned int)u) << 16; return v.f;
}
__device__ __forceinline__ float b2f(bf16 h) { return __bfloat162float(h); }
__device__ __forceinline__ bf16 f2b(float f) { return __float2bfloat16(f); }
__device__ __forceinline__ short f2bs(float f) { bf16 h = f2b(f); return *reinterpret_cast<short*>(&h); }
__device__ __forceinline__ unsigned pk2(float a, float b) {
    return (unsigned)(unsigned short)f2bs(a) | ((unsigned)(unsigned short)f2bs(b) << 16);
}
__device__ __forceinline__ float ldv(const bf16* p) { return b2f(*p); }
__device__ __forceinline__ float ldv(const float* p) { return *p; }
__device__ __forceinline__ void stv(bf16* p, float v) { *p = f2b(v); }
__device__ __forceinline__ void stv(float* p, float v) { *p = v; }
__device__ __forceinline__ float gelu_exact(float x) {
    return 0.5f * x * (1.0f + erff(x * 0.70710678118654752f));
}
__device__ __forceinline__ void async_lds16(const void* g, void* l) {
    __builtin_amdgcn_global_load_lds(
        (const __attribute__((address_space(1))) void*)g,
        (__attribute__((address_space(3))) void*)l, 16, 0, 0);
}

// ---------------- f32 -> bf16 conversion (6 mats) + zero-pad slots ----------------
__global__ __launch_bounds__(256)
void cvt8_kernel(const float* __restrict__ s0, bf16* __restrict__ d0, int n0,
                 const float* __restrict__ s1, bf16* __restrict__ d1, int n1,
                 const float* __restrict__ s2, bf16* __restrict__ d2, int n2,
                 const float* __restrict__ s3, bf16* __restrict__ d3, int n3,
                 const float* __restrict__ s4, bf16* __restrict__ d4, int n4,
                 const float* __restrict__ s5, bf16* __restrict__ d5, int n5)
{
    int i = blockIdx.x * 256 + threadIdx.x;
    if (i < n0) { d0[i] = f2b(s0[i]); return; } i -= n0;
    if (i < n1) { d1[i] = f2b(s1[i]); return; } i -= n1;
    if (i < n2) { d2[i] = f2b(s2[i]); return; } i -= n2;
    if (i < n3) { d3[i] = f2b(s3[i]); return; } i -= n3;
    if (i < n4) { d4[i] = f2b(s4[i]); return; } i -= n4;
    if (i < n5) { d5[i] = f2b(s5[i]); }
}

// ---------------- pack pw|proj into combined [192][384] bf16 weight ----------------
__global__ __launch_bounds__(256)
void cvtpack_kernel(const float* __restrict__ pw, const float* __restrict__ proj,
                    bf16* __restrict__ cmb)
{
    int i = blockIdx.x * 256 + threadIdx.x;   // 0 .. 2*192*192-1
    int half = CC * CC;
    if (i < half) {
        int n = i / CC, k = i - n * CC;
        cmb[(size_t)n * 384 + k] = f2b(pw[i]);
    } else {
        i -= half;
        int n = i / CC, k = i - n * CC;
        cmb[(size_t)n * 384 + 192 + k] = f2b(proj[i]);
    }
}

// ---------------- LayerNorm: one wave per row; optionally also emit bf16 copy of in --
template<typename IT>
__global__ __launch_bounds__(256)
void ln_kernel(const IT* __restrict__ in, const float* __restrict__ g,
               const float* __restrict__ bvec, bf16* __restrict__ out,
               bf16* __restrict__ xcopy)
{
    int wid = threadIdx.x >> 6, lane = threadIdx.x & 63;
    int row = blockIdx.x * 4 + wid;
    const IT* p = in + (size_t)row * CC;
    float x0 = ldv(p + lane);
    float x1 = ldv(p + lane + 64);
    float x2 = ldv(p + lane + 128);
    float s  = x0 + x1 + x2;
    float sq = x0*x0 + x1*x1 + x2*x2;
    #pragma unroll
    for (int o = 32; o > 0; o >>= 1) {
        s  += __shfl_xor(s,  o, 64);
        sq += __shfl_xor(sq, o, 64);
    }
    float mean = s * (1.0f / CC);
    float var  = sq * (1.0f / CC) - mean * mean;
    float inv  = rsqrtf(fmaxf(var, 0.0f) + 1e-5f);
    bf16* q = out + (size_t)row * CC;
    q[lane]       = f2b((x0 - mean) * inv * g[lane]       + bvec[lane]);
    q[lane + 64]  = f2b((x1 - mean) * inv * g[lane + 64]  + bvec[lane + 64]);
    q[lane + 128] = f2b((x2 - mean) * inv * g[lane + 128] + bvec[lane + 128]);
    if (xcopy) {
        bf16* xq = xcopy + (size_t)row * CC;
        xq[lane]       = f2b(x0);
        xq[lane + 64]  = f2b(x1);
        xq[lane + 128] = f2b(x2);
    }
}

// ---------------- MFMA GEMM (R12 config): block tile 128x64, BK=64, 4 waves ---------
// EPI: 0=none, 1=gelu, 2=modgate (out = acc + bias + b2f(xn2)*gate[b,c]).
// KA: A-buffer row stride. KA==KK: single A. KA<KK: split-K concat [A | A2]
// (A,A2 both [M,KA]; W is [NN,KK]). bf16 out staged via dead LDS -> 16B stores.
template<int EPI, bool RESID, int NN, int KK, int KA, typename RT, typename OT>
__global__ __launch_bounds__(256)
void mfma_gemm(const bf16* __restrict__ A, const bf16* __restrict__ A2,
               const bf16* __restrict__ W,
               const float* __restrict__ bias, const RT* __restrict__ resid,
               OT* __restrict__ out,
               const bf16* __restrict__ xn2, const float* __restrict__ gate)
{
    __shared__ __align__(16) short Smem[128 * 64 + 64 * 64];
    short* As = Smem;
    short* Bs = Smem + 128 * 64;
    const int t    = threadIdx.x;
    const int lane = t & 63;
    const int w    = t >> 6;        // wave 0..3
    const int nx   = gridDim.x;
    const int nwg  = gridDim.x * gridDim.y;
    int hw  = blockIdx.y * nx + blockIdx.x;
    int wid = (nwg & 7) ? hw : ((hw & 7) * (nwg >> 3) + (hw >> 3));
    const int m0   = (wid / nx) * 128;
    const int n0   = (wid % nx) * 64;
    const int lr   = lane & 15;
    const int lg   = lane >> 4;

    f32x4 acc[2][4];
    #pragma unroll
    for (int i = 0; i < 2; ++i)
        #pragma unroll
        for (int j = 0; j < 4; ++j)
            acc[i][j] = (f32x4){0.f, 0.f, 0.f, 0.f};

    for (int k0 = 0; k0 < KK; k0 += 64) {
        const bf16* Ab;
        if constexpr (KA < KK)
            Ab = (k0 < KA) ? A + (size_t)m0 * KA + k0
                           : A2 + (size_t)m0 * KA + (k0 - KA);
        else
            Ab = A + (size_t)m0 * KA + k0;
        const bf16* Wb = W + (size_t)n0 * KK + k0;
        #pragma unroll
        for (int li = 0; li < 4; ++li) {
            int chunk = li * 256 + t;
            int r = chunk >> 3, c = chunk & 7;
            int cs = c ^ (r & 7);
            async_lds16(Ab + (size_t)r * KA + (cs << 3),
                        &As[(li * 256 + w * 64) << 3]);
        }
        #pragma unroll
        for (int li = 0; li < 2; ++li) {
            int chunk = li * 256 + t;
            int r = chunk >> 3, c = chunk & 7;
            int cs = c ^ (r & 7);
            async_lds16(Wb + (size_t)r * KK + (cs << 3),
                        &Bs[(li * 256 + w * 64) << 3]);
        }
        __syncthreads();
        #pragma unroll
        for (int kf = 0; kf < 2; ++kf) {
            short8 a_[2], b_[4];
            #pragma unroll
            for (int mi = 0; mi < 2; ++mi) {
                int row = (w << 5) + (mi << 4) + lr;
                a_[mi] = *reinterpret_cast<const short8*>(
                    &As[(row << 6) + ((((kf << 2) + lg) ^ (row & 7)) << 3)]);
            }
            #pragma unroll
            for (int ni = 0; ni < 4; ++ni) {
                int rn = (ni << 4) + lr;
                b_[ni] = *reinterpret_cast<const short8*>(
                    &Bs[(rn << 6) + ((((kf << 2) + lg) ^ (rn & 7)) << 3)]);
            }
            #pragma unroll
            for (int mi = 0; mi < 2; ++mi)
                #pragma unroll
                for (int ni = 0; ni < 4; ++ni)
                    acc[mi][ni] = __builtin_amdgcn_mfma_f32_16x16x32_bf16(
                        a_[mi], b_[ni], acc[mi][ni], 0, 0, 0);
        }
        __syncthreads();
    }

    if constexpr (sizeof(OT) == 2) {
        short* cs = Smem + w * 3072;
        #pragma unroll
        for (int mi = 0; mi < 2; ++mi) {
            #pragma unroll
            for (int ni = 0; ni < 4; ++ni) {
                int col = n0 + (ni << 4) + lr;
                float bv = bias ? bias[col] : 0.f;
                #pragma unroll
                for (int r = 0; r < 4; ++r) {
                    int row = m0 + (w << 5) + (mi << 4) + (lg << 2) + r;
                    float c = acc[mi][ni][r] + bv;
                    if (EPI == 1) c = gelu_exact(c);
                    if (EPI == 2) {
                        int bidx = row / LL;
                        c += b2f(xn2[(size_t)row * NN + col]) * gate[bidx * CC + col];
                    }
                    if (RESID) c += ldv(resid + (size_t)row * NN + col);
                    cs[((mi << 4) + (lg << 2) + r) * 72 + (ni << 4) + lr] = f2bs(c);
                }
            }
        }
        #pragma unroll
        for (int pass = 0; pass < 4; ++pass) {
            int r8 = (lane >> 3) + (pass << 3);
            int c8 = lane & 7;
            uint4 v = *reinterpret_cast<const uint4*>(&cs[r8 * 72 + (c8 << 3)]);
            *reinterpret_cast<uint4*>((bf16*)out + (size_t)(m0 + (w << 5) + r8) * NN
                                      + n0 + (c8 << 3)) = v;
        }
    } else {
        #pragma unroll
        for (int mi = 0; mi < 2; ++mi) {
            #pragma unroll
            for (int ni = 0; ni < 4; ++ni) {
                int col = n0 + (ni << 4) + lr;
                float bv = bias ? bias[col] : 0.f;
                #pragma unroll
                for (int r = 0; r < 4; ++r) {
                    int row = m0 + (w << 5) + (mi << 4) + (lg << 2) + r;
                    float c = acc[mi][ni][r] + bv;
                    if (EPI == 1) c = gelu_exact(c);
                    if (EPI == 2) {
                        int bidx = row / LL;
                        c += b2f(xn2[(size_t)row * NN + col]) * gate[bidx * CC + col];
                    }
                    if (RESID) c += ldv(resid + (size_t)row * NN + col);
                    stv(out + (size_t)row * NN + col, c);
                }
            }
        }
    }
}

// ---------------- MFMA window attention v4: swapped QK^T, P in registers -------------
// 4 waves/block, one (window,head)/wave, no barriers.
__global__ __launch_bounds__(256)
void winattn_kernel(const bf16* __restrict__ qkv, bf16* __restrict__ aw)
{
    __shared__ __align__(16) short Buf[4][2560];

    const int w  = threadIdx.x >> 6;     // wave in block
    const int t  = threadIdx.x & 63;     // lane
    const int p  = blockIdx.x * 4 + w;   // pair index
    const int wi = p / 6;
    const int head = p - wi * 6;
    const int b  = wi >> 6;
    const int wr = wi & 63;
    const int wy = wr >> 3, wx = wr & 7;
    const int lc = t & 15;
    const int lg = t >> 4;
    const float scale = 0.1767766952966369f;   // 32^-0.5
    const bf16* qbase = qkv + (size_t)b * LL * C3 + head * HD;
    short* buf = Buf[w];

    // zero Vt region keys 48..63 (chunk-swizzled)
    #pragma unroll
    for (int e = t; e < 512; e += 64) {
        int d = e >> 4, k = 48 + (e & 15);
        buf[(d << 6) + (((k >> 3) ^ (d & 7)) << 3) + (k & 7)] = 0;
    }
    // stage V: Vt[d][k=tok], chunk-XOR swizzled, row stride 64 shorts
    for (int e = t; e < 196; e += 64) {
        int tok = e >> 2, part = e & 3;
        int iy = tok / 7, ix = tok - iy * 7;
        size_t l = (size_t)(wy * 7 + iy) * 56 + wx * 7 + ix;
        uint4 pv = *reinterpret_cast<const uint4*>(qbase + l * C3 + 384 + (part << 3));
        unsigned short uv[8];
        *reinterpret_cast<uint4*>(uv) = pv;
        #pragma unroll
        for (int jj = 0; jj < 8; ++jj) {
            int d = (part << 3) + jj;
            buf[(d << 6) + (((tok >> 3) ^ (d & 7)) << 3) + (tok & 7)] = (short)uv[jj];
        }
    }

    // K (A-frag) and Q (B-frag) direct from global (predicated)
    const short8 zero8 = {0, 0, 0, 0, 0, 0, 0, 0};
    short8 ka[4], qb[4];
    #pragma unroll
    for (int mi = 0; mi < 4; ++mi) {
        int key = (mi << 4) + lc;
        ka[mi] = zero8;
        if (key < 49) {
            int iy = key / 7, ix = key - iy * 7;
            size_t l = (size_t)(wy * 7 + iy) * 56 + wx * 7 + ix;
            ka[mi] = *reinterpret_cast<const short8*>(qbase + l * C3 + 192 + (lg << 3));
        }
    }
    #pragma unroll
    for (int nj = 0; nj < 4; ++nj) {
        int tok = (nj << 4) + lc;
        qb[nj] = zero8;
        if (tok < 49) {
            int iy = tok / 7, ix = tok - iy * 7;
            size_t l = (size_t)(wy * 7 + iy) * 56 + wx * 7 + ix;
            qb[nj] = *reinterpret_cast<const short8*>(qbase + l * C3 + (lg << 3));
        }
    }

    // S^T = K Q^T : acc[mi(key-tile)][nj(tok-tile)]
    f32x4 acc[4][4];
    #pragma unroll
    for (int i = 0; i < 4; ++i)
        #pragma unroll
        for (int j = 0; j < 4; ++j)
            acc[i][j] = (f32x4){0.f, 0.f, 0.f, 0.f};
    #pragma unroll
    for (int mi = 0; mi < 4; ++mi)
        #pragma unroll
        for (int nj = 0; nj < 4; ++nj)
            acc[mi][nj] = __builtin_amdgcn_mfma_f32_16x16x32_bf16(
                ka[mi], qb[nj], acc[mi][nj], 0, 0, 0);

    // softmax over keys (rows). keys mi<3 all valid; mi==3: only key 48 (lg==0,r==0).
    float rinv[4];
    #pragma unroll
    for (int nj = 0; nj < 4; ++nj) {
        float mx = acc[0][nj][0];
        #pragma unroll
        for (int mi = 0; mi < 3; ++mi)
            #pragma unroll
            for (int r = 0; r < 4; ++r)
                mx = fmaxf(mx, acc[mi][nj][r]);
        float v48 = (lg == 0) ? acc[3][nj][0] : -1e30f;
        mx = fmaxf(mx, v48);
        mx = fmaxf(mx, __shfl_xor(mx, 16, 64));
        mx = fmaxf(mx, __shfl_xor(mx, 32, 64));
        float sm = 0.f;
        #pragma unroll
        for (int mi = 0; mi < 3; ++mi)
            #pragma unroll
            for (int r = 0; r < 4; ++r) {
                float e = __expf(scale * (acc[mi][nj][r] - mx));
                acc[mi][nj][r] = e;
                sm += e;
            }
        float e48 = (lg == 0) ? __expf(scale * (acc[3][nj][0] - mx)) : 0.f;
        acc[3][nj][0] = e48; sm += e48;
        acc[3][nj][1] = 0.f; acc[3][nj][2] = 0.f; acc[3][nj][3] = 0.f;
        sm += __shfl_xor(sm, 16, 64);
        sm += __shfl_xor(sm, 32, 64);
        rinv[nj] = 1.0f / sm;
    }

    // O^T = V^T P^T : acc2[mi2(d-tile)][nj(tok-tile)]
    f32x4 acc2[2][4];
    #pragma unroll
    for (int i = 0; i < 2; ++i)
        #pragma unroll
        for (int j = 0; j < 4; ++j)
            acc2[i][j] = (f32x4){0.f, 0.f, 0.f, 0.f};
    const int src0 = ((lg & 1) << 5) + lc;
    const int src1 = src0 + 16;
    const bool hi = (lg >> 1) != 0;
    #pragma unroll
    for (int kf = 0; kf < 2; ++kf) {
        short8 av[2];
        #pragma unroll
        for (int mi2 = 0; mi2 < 2; ++mi2) {
            int d = (mi2 << 4) + lc;
            av[mi2] = *reinterpret_cast<const short8*>(
                &buf[(d << 6) + ((((kf << 2) + lg) ^ (d & 7)) << 3)]);
        }
        #pragma unroll
        for (int nj = 0; nj < 4; ++nj) {
            unsigned A0 = pk2(acc[2*kf][nj][0],   acc[2*kf][nj][1]);
            unsigned A1 = pk2(acc[2*kf][nj][2],   acc[2*kf][nj][3]);
            unsigned B0 = pk2(acc[2*kf+1][nj][0], acc[2*kf+1][nj][1]);
            unsigned B1 = pk2(acc[2*kf+1][nj][2], acc[2*kf+1][nj][3]);
            unsigned xa0 = __shfl(A0, src0, 64), xa1 = __shfl(A1, src0, 64);
            unsigned xa2 = __shfl(A0, src1, 64), xa3 = __shfl(A1, src1, 64);
            unsigned xb0 = __shfl(B0, src0, 64), xb1 = __shfl(B1, src0, 64);
            unsigned xb2 = __shfl(B0, src1, 64), xb3 = __shfl(B1, src1, 64);
            union { unsigned u[4]; short8 s; } ub;
            ub.u[0] = hi ? xb0 : xa0;
            ub.u[1] = hi ? xb1 : xa1;
            ub.u[2] = hi ? xb2 : xa2;
            ub.u[3] = hi ? xb3 : xa3;
            #pragma unroll
            for (int mi2 = 0; mi2 < 2; ++mi2)
                acc2[mi2][nj] = __builtin_amdgcn_mfma_f32_16x16x32_bf16(
                    av[mi2], ub.s, acc2[mi2][nj], 0, 0, 0);
        }
    }

    // normalized O -> Os[tok][d] (stride 40 shorts), then coalesced 16B stores.
    #pragma unroll
    for (int mi2 = 0; mi2 < 2; ++mi2)
        #pragma unroll
        for (int nj = 0; nj < 4; ++nj) {
            int tokrow = (nj << 4) + lc;
            #pragma unroll
            for (int r = 0; r < 4; ++r) {
                int d = (mi2 << 4) + (lg << 2) + r;
                buf[tokrow * 40 + d] = f2bs(acc2[mi2][nj][r] * rinv[nj]);
            }
        }
    for (int e = t; e < 196; e += 64) {
        int tok = e >> 2, part = e & 3;
        int iy = tok / 7, ix = tok - iy * 7;
        size_t l = (size_t)(wy * 7 + iy) * 56 + wx * 7 + ix;
        *reinterpret_cast<uint4*>(aw + ((size_t)b * LL + l) * CC + head * HD + (part << 3)) =
            *reinterpret_cast<const uint4*>(&buf[tok * 40 + (part << 3)]);
    }
}

// ---------------- Depthwise 3x3 (SAME) + exact GELU, vectorized 8-ch/thread ----------
__global__ __launch_bounds__(256)
void dwconv_kernel(const bf16* __restrict__ xn, const float* __restrict__ w,
                   bf16* __restrict__ out)
{
    __shared__ float wl[9 * 288];
    const int t = threadIdx.x;
    for (int i = t; i < CC * 9; i += 256) {
        int c = i / 9, k = i - c * 9;
        wl[k * 288 + (c >> 3) * 12 + (c & 7)] = w[i];
    }
    __syncthreads();
    int e = blockIdx.x * 256 + t;
    int cg = e % 24;
    int pix = e / 24;
    int w_ = pix % WW;
    int t2 = pix / WW;
    int h_ = t2 % HH;
    int b  = t2 / HH;
    float acc[8] = {0.f,0.f,0.f,0.f,0.f,0.f,0.f,0.f};
    const bf16* rowbase = xn + ((size_t)b * HH * WW) * CC + (size_t)cg * 8;
    #pragma unroll
    for (int ky = 0; ky < 3; ++ky) {
        int hy = h_ + ky - 1;
        if (hy < 0 || hy >= HH) continue;
        #pragma unroll
        for (int kx = 0; kx < 3; ++kx) {
            int wx_ = w_ + kx - 1;
            if (wx_ < 0 || wx_ >= WW) continue;
            int k = ky * 3 + kx;
            const float4* wp = reinterpret_cast<const float4*>(&wl[k * 288 + cg * 12]);
            float4 w0 = wp[0];
            float4 w1 = wp[1];
            unsigned short u[8];
            *reinterpret_cast<uint4*>(u) = *reinterpret_cast<const uint4*>(
                rowbase + ((size_t)hy * WW + wx_) * CC);
            acc[0] += us2f(u[0]) * w0.x;
            acc[1] += us2f(u[1]) * w0.y;
            acc[2] += us2f(u[2]) * w0.z;
            acc[3] += us2f(u[3]) * w0.w;
            acc[4] += us2f(u[4]) * w1.x;
            acc[5] += us2f(u[5]) * w1.y;
            acc[6] += us2f(u[6]) * w1.z;
            acc[7] += us2f(u[7]) * w1.w;
        }
    }
    bf16 o8[8];
    #pragma unroll
    for (int j = 0; j < 8; ++j) o8[j] = f2b(gelu_exact(acc[j]));
    *reinterpret_cast<uint4*>(out + (size_t)e * 8) = *reinterpret_cast<uint4*>(o8);
}

// ---------------- column (spatial) sum of xn per (b, c) ----------------
__global__ __launch_bounds__(192)
void colsum_kernel(const bf16* __restrict__ xn, float* __restrict__ colsum)
{
    int b = blockIdx.y, g = blockIdx.x, c = threadIdx.x;
    float acc = 0.f;
    int l0 = g * 196;
    for (int l = l0; l < l0 + 196; ++l)
        acc += b2f(xn[((size_t)b * LL + l) * CC + c]);
    atomicAdd(&colsum[b * CC + c], acc);
}

__global__ __launch_bounds__(192)
void gate_kernel(const float* __restrict__ colsum, const float* __restrict__ gw,
                 const float* __restrict__ gb, float* __restrict__ gate)
{
    __shared__ float cm[CC];
    int b = blockIdx.x, o = threadIdx.x;
    cm[o] = colsum[b * CC + o] * (1.0f / LL);
    __syncthreads();
    float acc = gb[o];
    for (int c = 0; c < CC; ++c) acc += gw[o * CC + c] * cm[c];
    gate[b * CC + o] = 1.0f / (1.0f + expf(-acc));
}

// ---------------- means over H and W in one launch, vec8, bf16 out ----------------
__global__ __launch_bounds__(256)
void means_kernel(const bf16* __restrict__ xf, bf16* __restrict__ mh,
                  bf16* __restrict__ mw)
{
    int e = blockIdx.x * 256 + threadIdx.x;
    const int NHALF = BB * WW * 24;
    if (e < NHALF) {
        int cg = e % 24, c0 = cg << 3;
        int w_ = (e / 24) % WW;
        int b  = e / (24 * WW);
        float s[8] = {0.f,0.f,0.f,0.f,0.f,0.f,0.f,0.f};
        const bf16* base = xf + ((size_t)b * HH * WW + w_) * CC + c0;
        for (int h_ = 0; h_ < HH; ++h_) {
            unsigned short u[8];
            *reinterpret_cast<uint4*>(u) = *reinterpret_cast<const uint4*>(base + (size_t)h_ * WW * CC);
            #pragma unroll
            for (int j = 0; j < 8; ++j) s[j] += us2f(u[j]);
        }
        bf16 o8[8];
        #pragma unroll
        for (int j = 0; j < 8; ++j) o8[j] = f2b(s[j] * (1.0f / HH));
        *reinterpret_cast<uint4*>(mh + ((size_t)b * WW + w_) * CC + c0) =
            *reinterpret_cast<uint4*>(o8);
    } else {
        e -= NHALF;
        int cg = e % 24, c0 = cg << 3;
        int h_ = (e / 24) % HH;
        int b  = e / (24 * HH);
        float s[8] = {0.f,0.f,0.f,0.f,0.f,0.f,0.f,0.f};
        const bf16* base = xf + ((size_t)b * HH + h_) * WW * CC + c0;
        for (int w_ = 0; w_ < WW; ++w_) {
            unsigned short u[8];
            *reinterpret_cast<uint4*>(u) = *reinterpret_cast<const uint4*>(base + (size_t)w_ * CC);
            #pragma unroll
            for (int j = 0; j < 8; ++j) s[j] += us2f(u[j]);
        }
        bf16 o8[8];
        #pragma unroll
        for (int j = 0; j < 8; ++j) o8[j] = f2b(s[j] * (1.0f / WW));
        *reinterpret_cast<uint4*>(mw + ((size_t)b * HH + h_) * CC + c0) =
            *reinterpret_cast<uint4*>(o8);
    }
}

// ---------------- MFMA axis softmax ----------------
__global__ __launch_bounds__(256)
void axmfma_kernel(const bf16* __restrict__ mh, const bf16* __restrict__ wt,
                   float* __restrict__ at,
                   const bf16* __restrict__ mw, const bf16* __restrict__ ws,
                   float* __restrict__ as_)
{
    const int b = blockIdx.x;
    const bf16* mean; const bf16* wmat; float* out;
    if (blockIdx.y == 0) { mean = mh; wmat = wt; out = at; }
    else                 { mean = mw; wmat = ws; out = as_; }
    const int w  = threadIdx.x >> 6;
    const int t  = threadIdx.x & 63;
    const int lc = t & 15, lg = t >> 4;
    const bf16* mb = mean + (size_t)b * 56 * CC;
    const short8 zero8 = {0, 0, 0, 0, 0, 0, 0, 0};

    f32x4 acc[3][4];
    #pragma unroll
    for (int i = 0; i < 3; ++i)
        #pragma unroll
        for (int j = 0; j < 4; ++j)
            acc[i][j] = (f32x4){0.f, 0.f, 0.f, 0.f};

    #pragma unroll
    for (int kf = 0; kf < 6; ++kf) {
        short8 a_[3], b_[4];
        #pragma unroll
        for (int mi = 0; mi < 3; ++mi) {
            int o = ((w * 3 + mi) << 4) + lc;
            a_[mi] = *reinterpret_cast<const short8*>(wmat + (size_t)o * CC + (kf << 5) + (lg << 3));
        }
        #pragma unroll
        for (int ni = 0; ni < 4; ++ni) {
            int pos = (ni << 4) + lc;
            b_[ni] = (pos < 56)
                ? *reinterpret_cast<const short8*>(mb + (size_t)pos * CC + (kf << 5) + (lg << 3))
                : zero8;
        }
        #pragma unroll
        for (int mi = 0; mi < 3; ++mi)
            #pragma unroll
            for (int ni = 0; ni < 4; ++ni)
                acc[mi][ni] = __builtin_amdgcn_mfma_f32_16x16x32_bf16(
                    a_[mi], b_[ni], acc[mi][ni], 0, 0, 0);
    }

    #pragma unroll
    for (int mi = 0; mi < 3; ++mi) {
        #pragma unroll
        for (int r = 0; r < 4; ++r) {
            float mx = -1e30f;
            #pragma unroll
            for (int ni = 0; ni < 4; ++ni) {
                float v = acc[mi][ni][r];
                if (ni == 3 && lc >= 8) v = -1e30f;
                mx = fmaxf(mx, v);
            }
            mx = fmaxf(mx, __shfl_xor(mx, 1, 64));
            mx = fmaxf(mx, __shfl_xor(mx, 2, 64));
            mx = fmaxf(mx, __shfl_xor(mx, 4, 64));
            mx = fmaxf(mx, __shfl_xor(mx, 8, 64));
            float e[4];
            float sm = 0.f;
            #pragma unroll
            for (int ni = 0; ni < 4; ++ni) {
                e[ni] = (ni == 3 && lc >= 8) ? 0.f : __expf(acc[mi][ni][r] - mx);
                sm += e[ni];
            }
            sm += __shfl_xor(sm, 1, 64);
            sm += __shfl_xor(sm, 2, 64);
            sm += __shfl_xor(sm, 4, 64);
            sm += __shfl_xor(sm, 8, 64);
            float inv = 1.0f / sm;
            int o = ((w * 3 + mi) << 4) + (lg << 2) + r;
            #pragma unroll
            for (int ni = 0; ni < 4; ++ni) {
                int pos = (ni << 4) + lc;
                if (pos < 56)
                    out[((size_t)b * 56 + pos) * CC + o] = e[ni] * inv;
            }
        }
    }
}

// ---------------- xf2 = xf * a_s[b,h,c] * a_t[b,w,c] * 2  (vec8, coalesced) ----------
__global__ __launch_bounds__(256)
void modulate_kernel(const bf16* __restrict__ xf, const float* __restrict__ a_s,
                     const float* __restrict__ a_t, bf16* __restrict__ xf2)
{
    int e = blockIdx.x * 256 + threadIdx.x;
    int cg = e % 24, c0 = cg << 3;
    int pix = e / 24;
    int w_ = pix % WW;
    int t2 = pix / WW;
    int h_ = t2 % HH;
    int b  = t2 / HH;
    unsigned short u[8];
    size_t base = (size_t)e * 8;
    *reinterpret_cast<uint4*>(u) = *reinterpret_cast<const uint4*>(xf + base);
    const float4* sp = reinterpret_cast<const float4*>(a_s + ((size_t)b * 56 + h_) * CC + c0);
    const float4* tp = reinterpret_cast<const float4*>(a_t + ((size_t)b * 56 + w_) * CC + c0);
    float4 s0 = sp[0], s1 = sp[1];
    float4 t0 = tp[0], t1 = tp[1];
    float ss[8] = {s0.x, s0.y, s0.z, s0.w, s1.x, s1.y, s1.z, s1.w};
    float tt[8] = {t0.x, t0.y, t0.z, t0.w, t1.x, t1.y, t1.z, t1.w};
    bf16 o8[8];
    #pragma unroll
    for (int j = 0; j < 8; ++j)
        o8[j] = f2b(us2f(u[j]) * ss[j] * tt[j] * 2.0f);
    *reinterpret_cast<uint4*>(xf2 + base) = *reinterpret_cast<uint4*>(o8);
}

// =======================================================================================
extern "C" void kernel_launch(void* const* d_in, const int* in_sizes, int n_in,
                              void* d_out, int out_size, void* d_ws, size_t ws_size,
                              hipStream_t stream)
{
    const float* x      = (const float*)d_in[0];
    const float* ln1_g  = (const float*)d_in[3];
    const float* ln1_b  = (const float*)d_in[4];
    const float* qkv_w  = (const float*)d_in[5];
    const float* qkv_b  = (const float*)d_in[6];
    const float* proj_w = (const float*)d_in[7];
    const float* proj_b = (const float*)d_in[8];
    const float* dw_w   = (const float*)d_in[9];
    const float* pw_w   = (const float*)d_in[10];
    const float* gate_w = (const float*)d_in[11];
    const float* gate_b = (const float*)d_in[12];
    const float* temp_w = (const float*)d_in[13];
    const float* spec_w = (const float*)d_in[15];
    const float* fuse_w = (const float*)d_in[17];
    const float* ln2_g  = (const float*)d_in[18];
    const float* ln2_b  = (const float*)d_in[19];
    const float* mlp1_w = (const float*)d_in[20];
    const float* mlp1_b = (const float*)d_in[21];
    const float* mlp2_w = (const float*)d_in[22];
    const float* mlp2_b = (const float*)d_in[23];
    float* out = (float*)d_out;

    const size_t SLOT = (size_t)MM * CC * sizeof(bf16);   // 38,535,168 B
    char* ws = (char*)d_ws;

    bf16* s_xn   = (bf16*)(ws);
    bf16* s_qkv  = (bf16*)(ws + SLOT);        // slots 1..3
    bf16* s_aw   = (bf16*)(ws + 4 * SLOT);
    bf16* s_dwg  = (bf16*)(ws + 2 * SLOT);    // overwrites qkv slot2 (qkv dead)
    bf16* s_xf   = (bf16*)(ws + 4 * SLOT);    // in-place over aw (merged gemm)
    bf16* s_xf2  = (bf16*)(ws + 3 * SLOT);    // qkv slot3 dead
    bf16* s_x2   = (bf16*)(ws);               // reuse xn (dead after merged gemm)
    bf16* s_hn   = (bf16*)(ws + 2 * SLOT);
    bf16* s_h1   = (bf16*)(ws + 3 * SLOT);    // spans slots 3..4

    float* colsum  = (float*)(ws + 5 * SLOT);
    float* gatebuf = colsum + BB * CC;
    bf16*  mean_h  = (bf16*)(gatebuf + BB * CC);
    bf16*  mean_w  = mean_h + (size_t)BB * 56 * CC;
    float* a_t     = (float*)(mean_w + (size_t)BB * 56 * CC);
    float* a_s     = a_t + (size_t)BB * CC * 56;
    // bf16 weight copies
    bf16* wb_qkv  = (bf16*)(a_s + (size_t)BB * CC * 56);
    bf16* wb_cmb  = wb_qkv  + C3 * CC;        // [192][384] = pw | proj
    bf16* wb_fuse = wb_cmb  + CC * 2 * CC;
    bf16* wb_mlp1 = wb_fuse + CC * CC;
    bf16* wb_mlp2 = wb_mlp1 + HIDN * CC;
    bf16* wb_temp = wb_mlp2 + CC * HIDN;
    bf16* wb_spec = wb_temp + CC * CC;
    char* after_w = (char*)(wb_spec + CC * CC);
    size_t total_need = after_w - ws;
    if (ws_size < total_need) return;   // workspace insufficient — visible failure
    bf16* s_xb = (bf16*)after_w;
    bool have_xb = (ws_size >= total_need + SLOT);

    const int VEC_BLOCKS = MM * 24 / 256;   // 9408, exact
    const int CVT_N0 = C3 * CC, CVT_N1 = CC * CC, CVT_N4 = HIDN * CC;
    const int CVT_TOTAL = CVT_N0 + 3 * CVT_N1 + 2 * CVT_N4;

    // 0. weight conversions
    cvt8_kernel<<<(CVT_TOTAL + 255) / 256, 256, 0, stream>>>(
        qkv_w, wb_qkv, CVT_N0, fuse_w, wb_fuse, CVT_N1,
        mlp1_w, wb_mlp1, CVT_N4, mlp2_w, wb_mlp2, CVT_N4,
        temp_w, wb_temp, CVT_N1, spec_w, wb_spec, CVT_N1);
    cvtpack_kernel<<<(2 * CC * CC + 255) / 256, 256, 0, stream>>>(pw_w, proj_w, wb_cmb);

    // 1. LN1 (+ optional bf16 x copy)
    ln_kernel<float><<<MM / 4, 256, 0, stream>>>(x, ln1_g, ln1_b, s_xn,
                                                 have_xb ? s_xb : nullptr);
    // 2. qkv
    mfma_gemm<0, false, C3, CC, CC, bf16, bf16><<<dim3(C3 / 64, MM / 128), 256, 0, stream>>>(
        s_xn, nullptr, wb_qkv, qkv_b, (const bf16*)nullptr, s_qkv, nullptr, nullptr);
    // 3. window attention (swapped QK^T, P in registers)
    winattn_kernel<<<NWIN * NHEAD / 4, 256, 0, stream>>>(s_qkv, s_aw);
    // 4. depthwise + gelu (vec8)  [overwrites qkv slot2; qkv dead after winattn]
    dwconv_kernel<<<VEC_BLOCKS, 256, 0, stream>>>(s_xn, dw_w, s_dwg);
    // 5. gate (needs only xn)
    hipMemsetAsync(colsum, 0, BB * CC * sizeof(float), stream);
    colsum_kernel<<<dim3(16, BB), 192, 0, stream>>>(s_xn, colsum);
    gate_kernel<<<BB, 192, 0, stream>>>(colsum, gate_w, gate_b, gatebuf);
    // 6. MERGED proj+pointwise+combine: xf = [dwg|aw] @ [pw|proj]^T + proj_b + xn*gate
    //    (in-place over aw: each block reads only its own m-rows before writing them)
    mfma_gemm<2, false, CC, 2 * CC, CC, bf16, bf16><<<dim3(CC / 64, MM / 128), 256, 0, stream>>>(
        s_dwg, s_aw, wb_cmb, proj_b, (const bf16*)nullptr, s_xf, s_xn, gatebuf);
    // 7. axis means (one launch, bf16 out)
    means_kernel<<<(2 * BB * WW * 24) / 256, 256, 0, stream>>>(s_xf, mean_h, mean_w);
    // 8. both axis softmaxes via MFMA
    axmfma_kernel<<<dim3(BB, 2), 256, 0, stream>>>(
        mean_h, wb_temp, a_t, mean_w, wb_spec, a_s);
    // 9. modulate (coalesced)
    modulate_kernel<<<VEC_BLOCKS, 256, 0, stream>>>(s_xf, a_s, a_t, s_xf2);
    // 10. fuse (no bias) + residual x -> x2
    if (have_xb)
        mfma_gemm<0, true, CC, CC, CC, bf16, bf16><<<dim3(CC / 64, MM / 128), 256, 0, stream>>>(
            s_xf2, nullptr, wb_fuse, (const float*)nullptr, s_xb, s_x2, nullptr, nullptr);
    else
        mfma_gemm<0, true, CC, CC, CC, float, bf16><<<dim3(CC / 64, MM / 128), 256, 0, stream>>>(
            s_xf2, nullptr, wb_fuse, (const float*)nullptr, x, s_x2, nullptr, nullptr);
    // 11. LN2
    ln_kernel<bf16><<<MM / 4, 256, 0, stream>>>(s_x2, ln2_g, ln2_b, s_hn, nullptr);
    // 12. MLP1 + gelu
    mfma_gemm<1, false, HIDN, CC, CC, bf16, bf16><<<dim3(HIDN / 64, MM / 128), 256, 0, stream>>>(
        s_hn, nullptr, wb_mlp1, mlp1_b, (const bf16*)nullptr, s_h1, nullptr, nullptr);
    // 13. MLP2 + residual -> out (f32)
    mfma_gemm<0, true, CC, HIDN, HIDN, bf16, float><<<dim3(CC / 64, MM / 128), 256, 0, stream>>>(
        s_h1, nullptr, wb_mlp2, mlp2_b, s_x2, out, nullptr, nullptr);
}